// Round 8
// baseline (3848.205 us; speedup 1.0000x reference)
//
#include <hip/hip_runtime.h>
#include <hip/hip_bf16.h>
#include <stdint.h>

typedef __bf16 bf16_t;
typedef bf16_t bf16x8 __attribute__((ext_vector_type(8)));
typedef float  f32x4  __attribute__((ext_vector_type(4)));
typedef float  f32x16 __attribute__((ext_vector_type(16)));

#define I_DIM 512
#define H_DIM 1024
#define B_DIM 64
#define S_DIM 512
#define G4    4096   // 4*H
#define CHUNK 16     // steps per xp ring slot
#define NCHUNK (S_DIM / CHUNK)
#define XPSLOT_ELEMS ((size_t)CHUNK * 64 * G4)   // 1024*4096 bf16 = 8 MB

// ---------------- workspace layout (bytes) — total ~34 MB ----------------
#define O_WXT   0x0000000ULL  // [4096][512]  bf16 = 4 MB   (packed WxT, row-major)
#define O_WHTF  0x0400000ULL  // [128][64][64][8] bf16 = 8 MB (Wh in MFMA B-frag order)
#define O_BIAS  0x0C00000ULL  // [4096] f32 = 16 KB
#define O_HBUF  0x0D00000ULL  // 2 slots * 128 KB (h in A-frag order) = 256 KB
#define O_BAR   0x0D40000ULL  // 32 KB counters: xp_done[] + consumed[] + h quarter-flags
#define O_XP    0x1200000ULL  // 2 slots * [1024][4096] bf16 = 16 MB

// bar[] u32 indices (64-spaced to avoid false sharing)
#define XPD_IDX(c)  (2048 + (c) * 64)   // xp chunk c published (256 arrivals)
#define CONS_IDX(c) (4096 + (c) * 64)   // xp chunk c consumed  (256 arrivals)
#define QF_BASE     6144                // h flags: [bh][quarter] regions of 64 u32;
                                        //   flag word = bar[QF_BASE + (bh*4+qt)*64 + (q&31)]

__device__ __forceinline__ float sigm(float x)      { return 1.f / (1.f + __expf(-x)); }
__device__ __forceinline__ float tanh_fast(float x) { return 1.f - 2.f / (__expf(2.f * x) + 1.f); }

// Packed gate-column permutation: packed col p = q*32 + g*8 + jj  <->  hidden j = q*8+jj, gate g (0:i 1:f 2:g 3:o)

__global__ void k_pack_wx(const float* __restrict__ w0, const float* __restrict__ w1,
                          const float* __restrict__ w2, const float* __restrict__ w3,
                          bf16_t* __restrict__ wxt) {
    int tid = blockIdx.x * 256 + threadIdx.x;
    int k = tid >> 12;
    int p = tid & 4095;
    int q = p >> 5, g = (p >> 3) & 3, jj = p & 7;
    int j = q * 8 + jj;
    const float* src = (g == 0) ? w0 : (g == 1) ? w1 : (g == 2) ? w2 : w3;
    wxt[(size_t)p * I_DIM + k] = (bf16_t)src[k * H_DIM + j];
}

// Wh -> global MFMA B-fragment order: whtf[q][ks][lane][8]
//   element = WhT[p = q*32 + (lane&31)][k = ks*16 + (lane>>5)*8 + e]
__global__ void k_pack_whf(const float* __restrict__ w0, const float* __restrict__ w1,
                           const float* __restrict__ w2, const float* __restrict__ w3,
                           bf16_t* __restrict__ whtf) {
    int idx = blockIdx.x * 256 + threadIdx.x;     // 0..4194303
    int e    = idx & 7;
    int lane = (idx >> 3) & 63;
    int ks   = (idx >> 9) & 63;
    int q    = idx >> 15;                          // 0..127
    int k = ks * 16 + (lane >> 5) * 8 + e;
    int c = lane & 31;
    int g = c >> 3, jj = c & 7;
    int j = q * 8 + jj;
    const float* src = (g == 0) ? w0 : (g == 1) ? w1 : (g == 2) ? w2 : w3;
    whtf[idx] = (bf16_t)src[k * H_DIM + j];
}

__global__ void k_pack_bias(const float* bi0, const float* bh0, const float* bi1, const float* bh1,
                            const float* bi2, const float* bh2, const float* bi3, const float* bh3,
                            float* __restrict__ bias) {
    int p = blockIdx.x * 256 + threadIdx.x;
    int q = p >> 5, g = (p >> 3) & 3, jj = p & 7;
    int j = q * 8 + jj;
    const float* a = (g == 0) ? bi0 : (g == 1) ? bi1 : (g == 2) ? bi2 : bi3;
    const float* b = (g == 0) ? bh0 : (g == 1) ? bh1 : (g == 2) ? bh2 : bh3;
    bias[p] = a[j] + b[j];
}

// ---------------- the whole LSTM in ONE persistent dispatch ----------------
// R14: per-wave quarter-gated h sync replaces the global tree barrier.
// R13 ledger: step 6.0us = exec ~1.8 + sync ~4.2 (tree mechanics ~2us:
// drain->grp RMW->root->epoch->128-poller observe->syncthreads release;
// plus ~2us straggler skew, fully serialized by the block-wide gate).
// Structural fact: consumer wave w reads ONLY h-quarter w, produced by the
// 32 WGs q in [w*32,(w+1)*32) of its half. New protocol:
//   producer q: h-slice stores -> vmcnt(0) -> OWN flag word = t+1
//               (no contended RMW anywhere)
//   consumer wave w: polls its quarter's 32 flags (one coalesced 128B
//               read/iter), proceeds independently — no release barrier.
// The existing Pl-reduce __syncthreads joins the 4 waves; since the 4
// wave-gates jointly cover all 128 producers of the half, a WG reaching
// the epilogue knows every producer published h_t, hence every WG finished
// reading h_{t-1} -> h slot WAR-safe (same induction as R8/R12).
// Critical path after last producer: drain + flag store + one poll RT
// ~0.75us; other quarters' h-load+MFMA overlap the wait (skew absorbed).
// xproj producer half (WGs 256..511) and xp ring pacing unchanged (R13).
__global__ __launch_bounds__(256, 2) void k_mega(
    const float* __restrict__ x, const bf16_t* __restrict__ wxt,
    const float* __restrict__ bias, const bf16_t* __restrict__ whtf,
    bf16_t* __restrict__ xp, bf16_t* __restrict__ hbuf,
    float* __restrict__ out, uint32_t* __restrict__ bar)
{
    __shared__ float Pl[4][16][64];               // step: partials, 16 KB
    __shared__ __align__(16) bf16_t Hlds[256];    // step: h staging
    __shared__ __align__(16) bf16_t Al[8 * 64 * 8];  // xproj: A tile, 8 KB
    __shared__ __align__(16) bf16_t Bl[8 * 64 * 8];  // xproj: B tile, 8 KB
    const int tid  = threadIdx.x;

    if (blockIdx.x >= 256) {
        // ---------------- xproj producer path ----------------
        const int xbid = blockIdx.x - 256;        // 0..255
        const int n0 = (xbid & 31) * 128;         // col tile
        const int rt = (xbid >> 5) * 128;         // row tile within chunk (0..896)
        const int wv = tid >> 6;
        const int lane = tid & 63;
        const int mq = wv >> 1, nq = wv & 1;
        const int l15 = lane & 15, quad = lane >> 4;

        for (int sc = 0; sc < NCHUNK; ++sc) {
            // Slot reuse gate: chunk sc writes slot sc&1, previously holding
            // chunk sc-2 — wait until all 256 step WGs consumed it.
            if (sc >= 2) {
                if (tid == 0) {
                    while (__hip_atomic_load(&bar[CONS_IDX(sc - 2)], __ATOMIC_RELAXED,
                                             __HIP_MEMORY_SCOPE_AGENT) < 256u)
                        __builtin_amdgcn_s_sleep(2);
                }
                __syncthreads();
            }
            bf16_t* xps = xp + (size_t)(sc & 1) * XPSLOT_ELEMS;
            const int r_base = sc * (CHUNK * 64);

            f32x4 acc[4][4] = {};
            for (int kk = 0; kk < I_DIM; kk += 32) {
                __syncthreads();
                #pragma unroll
                for (int sidx = 0; sidx < 2; ++sidx) {
                    int s = tid + sidx * 256;
                    int mt = s >> 6, l = s & 63;
                    int m = l & 15, kb = (l >> 4) * 8;
                    int r = r_base + rt + mt * 16 + m;
                    int b = r & 63, si = r >> 6;
                    const float* gp = x + ((size_t)(b * S_DIM + si)) * I_DIM + kk + kb;
                    float4 v0 = *(const float4*)gp;
                    float4 v1 = *(const float4*)(gp + 4);
                    bf16x8 a;
                    a[0] = (bf16_t)v0.x; a[1] = (bf16_t)v0.y; a[2] = (bf16_t)v0.z; a[3] = (bf16_t)v0.w;
                    a[4] = (bf16_t)v1.x; a[5] = (bf16_t)v1.y; a[6] = (bf16_t)v1.z; a[7] = (bf16_t)v1.w;
                    *(bf16x8*)&Al[s * 8] = a;
                    bf16x8 bv = *(const bf16x8*)(wxt + (size_t)(n0 + mt * 16 + m) * I_DIM + kk + kb);
                    *(bf16x8*)&Bl[s * 8] = bv;
                }
                __syncthreads();
                bf16x8 af[4], bfr[4];
                #pragma unroll
                for (int mt = 0; mt < 4; ++mt) af[mt]  = *(bf16x8*)&Al[((mq * 4 + mt) * 64 + lane) * 8];
                #pragma unroll
                for (int nt = 0; nt < 4; ++nt) bfr[nt] = *(bf16x8*)&Bl[((nq * 4 + nt) * 64 + lane) * 8];
                #pragma unroll
                for (int mt = 0; mt < 4; ++mt)
                    #pragma unroll
                    for (int nt = 0; nt < 4; ++nt)
                        acc[mt][nt] = __builtin_amdgcn_mfma_f32_16x16x32_bf16(af[mt], bfr[nt], acc[mt][nt], 0, 0, 0);
            }
            // Epilogue: agent-scope u16 stores (coherent for mid-dispatch read)
            #pragma unroll
            for (int nt = 0; nt < 4; ++nt) {
                int colg = n0 + nq * 64 + nt * 16 + l15;
                float bv = bias[colg];
                #pragma unroll
                for (int mt = 0; mt < 4; ++mt)
                    #pragma unroll
                    for (int r = 0; r < 4; ++r) {
                        int row = rt + mq * 64 + mt * 16 + quad * 4 + r;  // within chunk
                        bf16_t hb = (bf16_t)(acc[mt][nt][r] + bv);
                        __hip_atomic_store((uint16_t*)(xps + (size_t)row * G4 + colg),
                                           __builtin_bit_cast(unsigned short, hb),
                                           __ATOMIC_RELAXED, __HIP_MEMORY_SCOPE_AGENT);
                    }
            }
            asm volatile("s_waitcnt vmcnt(0)" ::: "memory");  // all lanes drained
            __syncthreads();                                   // all waves drained
            if (tid == 0)
                __hip_atomic_fetch_add(&bar[XPD_IDX(sc)], 1u,
                                       __ATOMIC_RELAXED, __HIP_MEMORY_SCOPE_AGENT);
        }
        return;
    }

    // ---------------- step path ----------------
    const int w    = tid >> 6;                    // K-quarter index
    const int lane = tid & 63;
    const int bid  = blockIdx.x;
    const int q    = bid & 127;                   // packed col-block (32 cols)
    const int bh   = bid >> 7;                    // batch half

    const int col  = lane & 31;
    const int ksel = lane >> 5;
    const int gt   = (lane >> 3) & 3;  // 0:i 1:f 2:g 3:o
    const int jj   = lane & 7;

    // h quarter-flag addresses: mine (producer) and my wave's poll region.
    uint32_t* myflag = bar + QF_BASE + ((bh * 4 + (q >> 5)) << 6) + (q & 31);
    const uint32_t* qfb = bar + QF_BASE + ((bh * 4 + w) << 6);

    int rrow[4];
    #pragma unroll
    for (int e = 0; e < 4; ++e) rrow[e] = e + 8 * w + 4 * ksel;

    // Loop-invariant B fragments: loaded ONCE for all 512 steps.
    const bf16_t* bb = whtf + ((size_t)q << 15) + (w << 13) + (lane << 3);
    bf16x8 bfr[16];
    #pragma unroll
    for (int i = 0; i < 16; ++i) bfr[i] = *(const bf16x8*)(bb + i * 512);

    // c-state in registers for the ENTIRE sequence (i-gate lanes only).
    float cst[4] = {0.f, 0.f, 0.f, 0.f};

    const int abase = (bh << 15) + (w << 13) + (lane << 3);  // h A-frag base (bf16 elements)

    for (int c = 0; c < NCHUNK; ++c) {
        // Wait for xp chunk c to be fully published (coarse, 1x per 16 steps).
        if (tid == 0) {
            while (__hip_atomic_load(&bar[XPD_IDX(c)], __ATOMIC_RELAXED,
                                     __HIP_MEMORY_SCOPE_AGENT) < 256u)
                __builtin_amdgcn_s_sleep(2);
        }
        __syncthreads();
        const uint16_t* xpc = (const uint16_t*)(xp + (size_t)(c & 1) * XPSLOT_ELEMS);

        for (int tl = 0; tl < CHUNK; ++tl) {
            const int t = c * CHUNK + tl;

            // xpr loads first (independent of h) — fly during the gate poll.
            bf16_t xpr[4];
            #pragma unroll
            for (int e = 0; e < 4; ++e) {
                unsigned short v = __hip_atomic_load(
                    &xpc[(size_t)(tl * 64 + bh * 32 + rrow[e]) * G4 + q * 32 + col],
                    __ATOMIC_RELAXED, __HIP_MEMORY_SCOPE_AGENT);
                xpr[e] = __builtin_bit_cast(bf16_t, v);
            }

            // Per-wave quarter gate: wait until all 32 producers of MY h
            // quarter published h_t. One coalesced 128B read per iteration.
            if (t > 0) {
                const uint32_t target = (uint32_t)t;
                while (__hip_atomic_load(&qfb[lane & 31], __ATOMIC_RELAXED,
                                         __HIP_MEMORY_SCOPE_AGENT) < target) {}
            }
            asm volatile("" ::: "memory");   // no hoisting of h loads above the gate

            // h loads: 32 relaxed agent u64 (L2-bypassing, coherent at L3).
            const uint64_t* hsrc = (const uint64_t*)(hbuf + ((t & 1) << 16) + abase);
            uint64_t hl0[16], hl1[16];
            #pragma unroll
            for (int i = 0; i < 16; ++i) {
                hl0[i] = __hip_atomic_load(hsrc + i * 128,     __ATOMIC_RELAXED, __HIP_MEMORY_SCOPE_AGENT);
                hl1[i] = __hip_atomic_load(hsrc + i * 128 + 1, __ATOMIC_RELAXED, __HIP_MEMORY_SCOPE_AGENT);
            }

            struct U2 { uint64_t a, b; };
            f32x16 acc0 = {}, acc1 = {}, acc2 = {}, acc3 = {};
            #pragma unroll
            for (int i = 0; i < 16; i += 4) {
                U2 t0{hl0[i + 0], hl1[i + 0]};
                U2 t1{hl0[i + 1], hl1[i + 1]};
                U2 t2{hl0[i + 2], hl1[i + 2]};
                U2 t3{hl0[i + 3], hl1[i + 3]};
                acc0 = __builtin_amdgcn_mfma_f32_32x32x16_bf16(__builtin_bit_cast(bf16x8, t0), bfr[i + 0], acc0, 0, 0, 0);
                acc1 = __builtin_amdgcn_mfma_f32_32x32x16_bf16(__builtin_bit_cast(bf16x8, t1), bfr[i + 1], acc1, 0, 0, 0);
                acc2 = __builtin_amdgcn_mfma_f32_32x32x16_bf16(__builtin_bit_cast(bf16x8, t2), bfr[i + 2], acc2, 0, 0, 0);
                acc3 = __builtin_amdgcn_mfma_f32_32x32x16_bf16(__builtin_bit_cast(bf16x8, t3), bfr[i + 3], acc3, 0, 0, 0);
            }
            f32x16 accs = acc0 + acc1 + acc2 + acc3;

            #pragma unroll
            for (int e = 0; e < 16; ++e) Pl[w][e][lane] = accs[e];
            __syncthreads();    // joins all 4 waves => all 4 quarter-gates passed
                                // => all 128 producers published h_t => h_{t-1}
                                // fully consumed by everyone => slot overwrite safe.

            #pragma unroll
            for (int e = 0; e < 4; ++e) {
                int eg = w * 4 + e;
                float pre = Pl[0][eg][lane] + Pl[1][eg][lane] + Pl[2][eg][lane] + Pl[3][eg][lane];
                pre += (float)xpr[e];
                float a = (gt == 2) ? tanh_fast(pre) : sigm(pre);

                float fv = __shfl_xor(a, 8, 64);
                float gv = __shfl_xor(a, 16, 64);
                float ov = __shfl_xor(a, 24, 64);
                if (gt == 0) {
                    float cn = fv * cst[e] + a * gv;
                    float hv = ov * tanh_fast(cn);
                    cst[e] = cn;
                    Hlds[rrow[e] * 8 + jj] = (bf16_t)hv;
                    if (t == S_DIM - 1) {
                        int rowg = bh * 32 + rrow[e];
                        int j = q * 8 + jj;
                        out[rowg * H_DIM + j] = hv;            // h_T
                        out[65536 + rowg * H_DIM + j] = cn;    // c_T
                    }
                }
            }
            __syncthreads();   // Hlds complete (wave 0 reads it right after;
                               // next step's Hlds writes are behind the next
                               // Pl-__syncthreads, which wave 0 also joins)

            // Publish h slice (wave 0): stores -> drain -> own flag. No
            // block-wide release — consumers gate per-wave on the flags.
            if (w == 0) {
                uint64_t v = *(const uint64_t*)&Hlds[lane * 4];
                uint64_t* hdst = (uint64_t*)hbuf + (((t + 1) & 1) << 14)
                               + (bh << 13) + (q << 6) + lane;
                __hip_atomic_store(hdst, v, __ATOMIC_RELAXED, __HIP_MEMORY_SCOPE_AGENT);
                if (t < S_DIM - 1) {
                    asm volatile("s_waitcnt vmcnt(0)" ::: "memory");  // h store at L3
                    if (lane == 0)
                        __hip_atomic_store(myflag, (uint32_t)(t + 1),
                                           __ATOMIC_RELAXED, __HIP_MEMORY_SCOPE_AGENT);
                }
            }
        }

        // Chunk consumed: xproj may overwrite this xp slot (for chunk c+2).
        // (The last __syncthreads above joined all waves after their xpr reads.)
        if (tid == 0)
            __hip_atomic_fetch_add(&bar[CONS_IDX(c)], 1u,
                                   __ATOMIC_RELAXED, __HIP_MEMORY_SCOPE_AGENT);
    }
}

extern "C" void kernel_launch(void* const* d_in, const int* in_sizes, int n_in,
                              void* d_out, int out_size, void* d_ws, size_t ws_size,
                              hipStream_t stream) {
    const float* x   = (const float*)d_in[0];
    const float* wii = (const float*)d_in[1];
    const float* bii = (const float*)d_in[2];
    const float* whi = (const float*)d_in[3];
    const float* bhi = (const float*)d_in[4];
    const float* wif = (const float*)d_in[5];
    const float* bif = (const float*)d_in[6];
    const float* whf = (const float*)d_in[7];
    const float* bhf = (const float*)d_in[8];
    const float* wig = (const float*)d_in[9];
    const float* big = (const float*)d_in[10];
    const float* whg = (const float*)d_in[11];
    const float* bhg = (const float*)d_in[12];
    const float* wio = (const float*)d_in[13];
    const float* bio = (const float*)d_in[14];
    const float* who = (const float*)d_in[15];
    const float* bho = (const float*)d_in[16];

    char* ws = (char*)d_ws;
    bf16_t*   wxt  = (bf16_t*)(ws + O_WXT);
    bf16_t*   whtf = (bf16_t*)(ws + O_WHTF);
    float*    bias = (float*)(ws + O_BIAS);
    bf16_t*   hbuf = (bf16_t*)(ws + O_HBUF);
    uint32_t* bar  = (uint32_t*)(ws + O_BAR);
    bf16_t*   xp   = (bf16_t*)(ws + O_XP);

    hipMemsetAsync(hbuf, 0, 256 * 1024, stream);   // both h slots = 0 (h0)
    hipMemsetAsync(bar,  0, 32 * 1024, stream);    // all counters (reset each replay)

    k_pack_wx<<<8192, 256, 0, stream>>>(wii, wif, wig, wio, wxt);
    k_pack_whf<<<16384, 256, 0, stream>>>(whi, whf, whg, who, whtf);
    k_pack_bias<<<16, 256, 0, stream>>>(bii, bhi, bif, bhf, big, bhg, bio, bho, bias);

    float* out = (float*)d_out;
    void* args[] = { (void*)&x, (void*)&wxt, (void*)&bias, (void*)&whtf,
                     (void*)&xp, (void*)&hbuf, (void*)&out, (void*)&bar };
    hipError_t err = hipLaunchCooperativeKernel((const void*)k_mega, dim3(512), dim3(256),
                                                args, 0, stream);
    if (err != hipSuccess) {
        // Plain-launch fallback: capacity (2 blocks/CU x 256 CU) == grid, so
        // all 512 blocks are co-resident regardless of dispatch order.
        k_mega<<<512, 256, 0, stream>>>(x, wxt, bias, whtf, xp, hbuf, out, bar);
    }
}

// Round 9
// 3194.498 us; speedup vs baseline: 1.2046x; 1.2046x over previous
//
#include <hip/hip_runtime.h>
#include <hip/hip_bf16.h>
#include <stdint.h>

typedef __bf16 bf16_t;
typedef bf16_t bf16x8 __attribute__((ext_vector_type(8)));
typedef float  f32x4  __attribute__((ext_vector_type(4)));
typedef float  f32x16 __attribute__((ext_vector_type(16)));

#define I_DIM 512
#define H_DIM 1024
#define B_DIM 64
#define S_DIM 512
#define G4    4096   // 4*H
#define CHUNK 16     // steps per xp ring slot
#define NCHUNK (S_DIM / CHUNK)
#define XPSLOT_ELEMS ((size_t)CHUNK * 64 * G4)   // 1024*4096 bf16 = 8 MB

// ---------------- workspace layout (bytes) — total ~34 MB ----------------
#define O_WXT   0x0000000ULL  // [4096][512]  bf16 = 4 MB   (packed WxT, row-major)
#define O_WHTF  0x0400000ULL  // [128][64][64][8] bf16 = 8 MB (Wh in MFMA B-frag order)
#define O_BIAS  0x0C00000ULL  // [4096] f32 = 16 KB
#define O_HBUF  0x0D00000ULL  // 2 slots * 128 KB (h in A-frag order) = 256 KB
#define O_BAR   0x0D40000ULL  // 32 KB counters: tree barrier + xp_done[] + consumed[]
#define O_XP    0x1200000ULL  // 2 slots * [1024][4096] bf16 = 16 MB

// bar[] u32 indices (64-spaced to avoid false sharing)
#define XPD_IDX(c)  (2048 + (c) * 64)   // xp chunk c published (256 arrivals)
#define CONS_IDX(c) (4096 + (c) * 64)   // xp chunk c consumed  (256 arrivals)

__device__ __forceinline__ float sigm(float x)      { return 1.f / (1.f + __expf(-x)); }
__device__ __forceinline__ float tanh_fast(float x) { return 1.f - 2.f / (__expf(2.f * x) + 1.f); }

// Packed gate-column permutation: packed col p = q*32 + g*8 + jj  <->  hidden j = q*8+jj, gate g (0:i 1:f 2:g 3:o)

__global__ void k_pack_wx(const float* __restrict__ w0, const float* __restrict__ w1,
                          const float* __restrict__ w2, const float* __restrict__ w3,
                          bf16_t* __restrict__ wxt) {
    int tid = blockIdx.x * 256 + threadIdx.x;
    int k = tid >> 12;
    int p = tid & 4095;
    int q = p >> 5, g = (p >> 3) & 3, jj = p & 7;
    int j = q * 8 + jj;
    const float* src = (g == 0) ? w0 : (g == 1) ? w1 : (g == 2) ? w2 : w3;
    wxt[(size_t)p * I_DIM + k] = (bf16_t)src[k * H_DIM + j];
}

// Wh -> global MFMA B-fragment order: whtf[q][ks][lane][8]
//   element = WhT[p = q*32 + (lane&31)][k = ks*16 + (lane>>5)*8 + e]
__global__ void k_pack_whf(const float* __restrict__ w0, const float* __restrict__ w1,
                           const float* __restrict__ w2, const float* __restrict__ w3,
                           bf16_t* __restrict__ whtf) {
    int idx = blockIdx.x * 256 + threadIdx.x;     // 0..4194303
    int e    = idx & 7;
    int lane = (idx >> 3) & 63;
    int ks   = (idx >> 9) & 63;
    int q    = idx >> 15;                          // 0..127
    int k = ks * 16 + (lane >> 5) * 8 + e;
    int c = lane & 31;
    int g = c >> 3, jj = c & 7;
    int j = q * 8 + jj;
    const float* src = (g == 0) ? w0 : (g == 1) ? w1 : (g == 2) ? w2 : w3;
    whtf[idx] = (bf16_t)src[k * H_DIM + j];
}

__global__ void k_pack_bias(const float* bi0, const float* bh0, const float* bi1, const float* bh1,
                            const float* bi2, const float* bh2, const float* bi3, const float* bh3,
                            float* __restrict__ bias) {
    int p = blockIdx.x * 256 + threadIdx.x;
    int q = p >> 5, g = (p >> 3) & 3, jj = p & 7;
    int j = q * 8 + jj;
    const float* a = (g == 0) ? bi0 : (g == 1) ? bi1 : (g == 2) ? bi2 : bi3;
    const float* b = (g == 0) ? bh0 : (g == 1) ? bh1 : (g == 2) ? bh2 : bh3;
    bias[p] = a[j] + b[j];
}

// ---------------- the whole LSTM in ONE persistent dispatch ----------------
// R15 = R13 (best: 3171) + two quantified fixes. Sync ledger across 7
// designs: tree+single-epoch-poll (R8/R13: 4.93-6.0 us/step) beats ALL
// distributed-flag designs (R10/R11/R14: 7.5-8.6) — polling must hit O(1)
// addresses. R14's per-wave gates put 1024 spinning waves x 128B reads on
// L3 and throttled the producers (VALUBusy 10.5->8.5).
// Fix 1 (interference): R12/R13 delta shows xproj co-residency costs
//   ~0.4-1 us/step; step waves are 85% issue-idle. s_setprio(1) on the
//   step path (T5 — waves at different phases on one CU); xproj at prio 0
//   fills stall slots. xproj needs ~1/16 of the machine to keep pace.
// Fix 2 (serial chain): merge root->epoch. Leaders increment root; pollers
//   wait root >= 8*(t+1). One less L3 RMW RT per step (~0.3-0.4 us).
// All else identical to R13.
__global__ __launch_bounds__(256, 2) void k_mega(
    const float* __restrict__ x, const bf16_t* __restrict__ wxt,
    const float* __restrict__ bias, const bf16_t* __restrict__ whtf,
    bf16_t* __restrict__ xp, bf16_t* __restrict__ hbuf,
    float* __restrict__ out, uint32_t* __restrict__ bar)
{
    __shared__ float Pl[4][16][64];               // step: partials, 16 KB
    __shared__ __align__(16) bf16_t Hlds[256];    // step: h staging
    __shared__ __align__(16) bf16_t Al[8 * 64 * 8];  // xproj: A tile, 8 KB
    __shared__ __align__(16) bf16_t Bl[8 * 64 * 8];  // xproj: B tile, 8 KB
    const int tid  = threadIdx.x;

    if (blockIdx.x >= 256) {
        // ---------------- xproj producer path (prio 0) ----------------
        const int xbid = blockIdx.x - 256;        // 0..255
        const int n0 = (xbid & 31) * 128;         // col tile
        const int rt = (xbid >> 5) * 128;         // row tile within chunk (0..896)
        const int wv = tid >> 6;
        const int lane = tid & 63;
        const int mq = wv >> 1, nq = wv & 1;
        const int l15 = lane & 15, quad = lane >> 4;

        for (int sc = 0; sc < NCHUNK; ++sc) {
            // Slot reuse gate: chunk sc writes slot sc&1, previously holding
            // chunk sc-2 — wait until all 256 step WGs consumed it.
            if (sc >= 2) {
                if (tid == 0) {
                    while (__hip_atomic_load(&bar[CONS_IDX(sc - 2)], __ATOMIC_RELAXED,
                                             __HIP_MEMORY_SCOPE_AGENT) < 256u)
                        __builtin_amdgcn_s_sleep(2);
                }
                __syncthreads();
            }
            bf16_t* xps = xp + (size_t)(sc & 1) * XPSLOT_ELEMS;
            const int r_base = sc * (CHUNK * 64);

            f32x4 acc[4][4] = {};
            for (int kk = 0; kk < I_DIM; kk += 32) {
                __syncthreads();
                #pragma unroll
                for (int sidx = 0; sidx < 2; ++sidx) {
                    int s = tid + sidx * 256;
                    int mt = s >> 6, l = s & 63;
                    int m = l & 15, kb = (l >> 4) * 8;
                    int r = r_base + rt + mt * 16 + m;
                    int b = r & 63, si = r >> 6;
                    const float* gp = x + ((size_t)(b * S_DIM + si)) * I_DIM + kk + kb;
                    float4 v0 = *(const float4*)gp;
                    float4 v1 = *(const float4*)(gp + 4);
                    bf16x8 a;
                    a[0] = (bf16_t)v0.x; a[1] = (bf16_t)v0.y; a[2] = (bf16_t)v0.z; a[3] = (bf16_t)v0.w;
                    a[4] = (bf16_t)v1.x; a[5] = (bf16_t)v1.y; a[6] = (bf16_t)v1.z; a[7] = (bf16_t)v1.w;
                    *(bf16x8*)&Al[s * 8] = a;
                    bf16x8 bv = *(const bf16x8*)(wxt + (size_t)(n0 + mt * 16 + m) * I_DIM + kk + kb);
                    *(bf16x8*)&Bl[s * 8] = bv;
                }
                __syncthreads();
                bf16x8 af[4], bfr[4];
                #pragma unroll
                for (int mt = 0; mt < 4; ++mt) af[mt]  = *(bf16x8*)&Al[((mq * 4 + mt) * 64 + lane) * 8];
                #pragma unroll
                for (int nt = 0; nt < 4; ++nt) bfr[nt] = *(bf16x8*)&Bl[((nq * 4 + nt) * 64 + lane) * 8];
                #pragma unroll
                for (int mt = 0; mt < 4; ++mt)
                    #pragma unroll
                    for (int nt = 0; nt < 4; ++nt)
                        acc[mt][nt] = __builtin_amdgcn_mfma_f32_16x16x32_bf16(af[mt], bfr[nt], acc[mt][nt], 0, 0, 0);
            }
            // Epilogue: agent-scope u16 stores (coherent for mid-dispatch read)
            #pragma unroll
            for (int nt = 0; nt < 4; ++nt) {
                int colg = n0 + nq * 64 + nt * 16 + l15;
                float bv = bias[colg];
                #pragma unroll
                for (int mt = 0; mt < 4; ++mt)
                    #pragma unroll
                    for (int r = 0; r < 4; ++r) {
                        int row = rt + mq * 64 + mt * 16 + quad * 4 + r;  // within chunk
                        bf16_t hb = (bf16_t)(acc[mt][nt][r] + bv);
                        __hip_atomic_store((uint16_t*)(xps + (size_t)row * G4 + colg),
                                           __builtin_bit_cast(unsigned short, hb),
                                           __ATOMIC_RELAXED, __HIP_MEMORY_SCOPE_AGENT);
                    }
            }
            asm volatile("s_waitcnt vmcnt(0)" ::: "memory");  // all lanes drained
            __syncthreads();                                   // all waves drained
            if (tid == 0)
                __hip_atomic_fetch_add(&bar[XPD_IDX(sc)], 1u,
                                       __ATOMIC_RELAXED, __HIP_MEMORY_SCOPE_AGENT);
        }
        return;
    }

    // ---------------- step path (prio 1: wins CU arbitration vs xproj) ----
    __builtin_amdgcn_s_setprio(1);

    const int w    = tid >> 6;                    // K-quarter index
    const int lane = tid & 63;
    const int bid  = blockIdx.x;
    const int q    = bid & 127;                   // packed col-block (32 cols)
    const int bh   = bid >> 7;                    // batch half

    const int col  = lane & 31;
    const int ksel = lane >> 5;
    const int gt   = (lane >> 3) & 3;  // 0:i 1:f 2:g 3:o
    const int jj   = lane & 7;

    // Per-half barrier tree (monotonic u32, 64-spaced):
    //   group[bh][g]: bar[(bh*8+g)*64], g = q&7, 16 arrivals/episode
    //   root[bh]:     bar[1024 + bh*64], 8 leader increments/episode
    // Pollers wait root >= 8*(t+1)  (epoch tier merged into root).
    uint32_t* grp  = bar + ((bh * 8 + (q & 7)) << 6);
    uint32_t* root = bar + 1024 + (bh << 6);

    int rrow[4];
    #pragma unroll
    for (int e = 0; e < 4; ++e) rrow[e] = e + 8 * w + 4 * ksel;

    // Loop-invariant B fragments: loaded ONCE for all 512 steps.
    const bf16_t* bb = whtf + ((size_t)q << 15) + (w << 13) + (lane << 3);
    bf16x8 bfr[16];
    #pragma unroll
    for (int i = 0; i < 16; ++i) bfr[i] = *(const bf16x8*)(bb + i * 512);

    // c-state in registers for the ENTIRE sequence (i-gate lanes only).
    float cst[4] = {0.f, 0.f, 0.f, 0.f};

    const int abase = (bh << 15) + (w << 13) + (lane << 3);  // h A-frag base (bf16 elements)

    for (int c = 0; c < NCHUNK; ++c) {
        // Wait for xp chunk c to be fully published (coarse, 1x per 16 steps).
        if (tid == 0) {
            while (__hip_atomic_load(&bar[XPD_IDX(c)], __ATOMIC_RELAXED,
                                     __HIP_MEMORY_SCOPE_AGENT) < 256u)
                __builtin_amdgcn_s_sleep(2);
        }
        __syncthreads();
        const uint16_t* xpc = (const uint16_t*)(xp + (size_t)(c & 1) * XPSLOT_ELEMS);

        for (int tl = 0; tl < CHUNK; ++tl) {
            const int t = c * CHUNK + tl;

            // h loads upfront — availability guaranteed by previous step's barrier.
            const uint64_t* hsrc = (const uint64_t*)(hbuf + ((t & 1) << 16) + abase);
            uint64_t hl0[16], hl1[16];
            #pragma unroll
            for (int i = 0; i < 16; ++i) {
                hl0[i] = __hip_atomic_load(hsrc + i * 128,     __ATOMIC_RELAXED, __HIP_MEMORY_SCOPE_AGENT);
                hl1[i] = __hip_atomic_load(hsrc + i * 128 + 1, __ATOMIC_RELAXED, __HIP_MEMORY_SCOPE_AGENT);
            }

            // xpr: agent u16 loads (xp produced mid-dispatch on other XCDs)
            bf16_t xpr[4];
            #pragma unroll
            for (int e = 0; e < 4; ++e) {
                unsigned short v = __hip_atomic_load(
                    &xpc[(size_t)(tl * 64 + bh * 32 + rrow[e]) * G4 + q * 32 + col],
                    __ATOMIC_RELAXED, __HIP_MEMORY_SCOPE_AGENT);
                xpr[e] = __builtin_bit_cast(bf16_t, v);
            }

            struct U2 { uint64_t a, b; };
            f32x16 acc0 = {}, acc1 = {}, acc2 = {}, acc3 = {};
            #pragma unroll
            for (int i = 0; i < 16; i += 4) {
                U2 t0{hl0[i + 0], hl1[i + 0]};
                U2 t1{hl0[i + 1], hl1[i + 1]};
                U2 t2{hl0[i + 2], hl1[i + 2]};
                U2 t3{hl0[i + 3], hl1[i + 3]};
                acc0 = __builtin_amdgcn_mfma_f32_32x32x16_bf16(__builtin_bit_cast(bf16x8, t0), bfr[i + 0], acc0, 0, 0, 0);
                acc1 = __builtin_amdgcn_mfma_f32_32x32x16_bf16(__builtin_bit_cast(bf16x8, t1), bfr[i + 1], acc1, 0, 0, 0);
                acc2 = __builtin_amdgcn_mfma_f32_32x32x16_bf16(__builtin_bit_cast(bf16x8, t2), bfr[i + 2], acc2, 0, 0, 0);
                acc3 = __builtin_amdgcn_mfma_f32_32x32x16_bf16(__builtin_bit_cast(bf16x8, t3), bfr[i + 3], acc3, 0, 0, 0);
            }
            f32x16 accs = acc0 + acc1 + acc2 + acc3;

            #pragma unroll
            for (int e = 0; e < 16; ++e) Pl[w][e][lane] = accs[e];
            __syncthreads();

            #pragma unroll
            for (int e = 0; e < 4; ++e) {
                int eg = w * 4 + e;
                float pre = Pl[0][eg][lane] + Pl[1][eg][lane] + Pl[2][eg][lane] + Pl[3][eg][lane];
                pre += (float)xpr[e];
                float a = (gt == 2) ? tanh_fast(pre) : sigm(pre);

                float fv = __shfl_xor(a, 8, 64);
                float gv = __shfl_xor(a, 16, 64);
                float ov = __shfl_xor(a, 24, 64);
                if (gt == 0) {
                    float cn = fv * cst[e] + a * gv;
                    float hv = ov * tanh_fast(cn);
                    cst[e] = cn;
                    Hlds[rrow[e] * 8 + jj] = (bf16_t)hv;
                    if (t == S_DIM - 1) {
                        int rowg = bh * 32 + rrow[e];
                        int j = q * 8 + jj;
                        out[rowg * H_DIM + j] = hv;            // h_T
                        out[65536 + rowg * H_DIM + j] = cn;    // c_T
                    }
                }
            }
            __syncthreads();   // Hlds complete; also fences Pl reuse next step

            // Publish h slice (wave 0), drain, tree arrive + poll (lane 0).
            if (w == 0) {
                uint64_t v = *(const uint64_t*)&Hlds[lane * 4];
                uint64_t* hdst = (uint64_t*)hbuf + (((t + 1) & 1) << 14)
                               + (bh << 13) + (q << 6) + lane;
                __hip_atomic_store(hdst, v, __ATOMIC_RELAXED, __HIP_MEMORY_SCOPE_AGENT);
                if (t < S_DIM - 1) {
                    asm volatile("s_waitcnt vmcnt(0)" ::: "memory");  // h store at L3
                    if (lane == 0) {
                        uint32_t old = __hip_atomic_fetch_add(grp, 1u,
                                                              __ATOMIC_RELAXED, __HIP_MEMORY_SCOPE_AGENT);
                        if ((old & 15u) == 15u)                      // 16 arrivals -> leader
                            __hip_atomic_fetch_add(root, 1u,
                                                   __ATOMIC_RELAXED, __HIP_MEMORY_SCOPE_AGENT);
                        uint32_t target = (uint32_t)(8 * (t + 1));
                        while (__hip_atomic_load(root, __ATOMIC_RELAXED,
                                                 __HIP_MEMORY_SCOPE_AGENT) < target) {}
                    }
                }
            }
            if (t < S_DIM - 1) __syncthreads();   // release all waves
        }

        // Chunk consumed: xproj may overwrite this xp slot (for chunk c+2).
        if (tid == 0)
            __hip_atomic_fetch_add(&bar[CONS_IDX(c)], 1u,
                                   __ATOMIC_RELAXED, __HIP_MEMORY_SCOPE_AGENT);
    }
}

extern "C" void kernel_launch(void* const* d_in, const int* in_sizes, int n_in,
                              void* d_out, int out_size, void* d_ws, size_t ws_size,
                              hipStream_t stream) {
    const float* x   = (const float*)d_in[0];
    const float* wii = (const float*)d_in[1];
    const float* bii = (const float*)d_in[2];
    const float* whi = (const float*)d_in[3];
    const float* bhi = (const float*)d_in[4];
    const float* wif = (const float*)d_in[5];
    const float* bif = (const float*)d_in[6];
    const float* whf = (const float*)d_in[7];
    const float* bhf = (const float*)d_in[8];
    const float* wig = (const float*)d_in[9];
    const float* big = (const float*)d_in[10];
    const float* whg = (const float*)d_in[11];
    const float* bhg = (const float*)d_in[12];
    const float* wio = (const float*)d_in[13];
    const float* bio = (const float*)d_in[14];
    const float* who = (const float*)d_in[15];
    const float* bho = (const float*)d_in[16];

    char* ws = (char*)d_ws;
    bf16_t*   wxt  = (bf16_t*)(ws + O_WXT);
    bf16_t*   whtf = (bf16_t*)(ws + O_WHTF);
    float*    bias = (float*)(ws + O_BIAS);
    bf16_t*   hbuf = (bf16_t*)(ws + O_HBUF);
    uint32_t* bar  = (uint32_t*)(ws + O_BAR);
    bf16_t*   xp   = (bf16_t*)(ws + O_XP);

    hipMemsetAsync(hbuf, 0, 256 * 1024, stream);   // both h slots = 0 (h0)
    hipMemsetAsync(bar,  0, 32 * 1024, stream);    // all counters (reset each replay)

    k_pack_wx<<<8192, 256, 0, stream>>>(wii, wif, wig, wio, wxt);
    k_pack_whf<<<16384, 256, 0, stream>>>(whi, whf, whg, who, whtf);
    k_pack_bias<<<16, 256, 0, stream>>>(bii, bhi, bif, bhf, big, bhg, bio, bho, bias);

    float* out = (float*)d_out;
    void* args[] = { (void*)&x, (void*)&wxt, (void*)&bias, (void*)&whtf,
                     (void*)&xp, (void*)&hbuf, (void*)&out, (void*)&bar };
    hipError_t err = hipLaunchCooperativeKernel((const void*)k_mega, dim3(512), dim3(256),
                                                args, 0, stream);
    if (err != hipSuccess) {
        // Plain-launch fallback: capacity (2 blocks/CU x 256 CU) == grid, so
        // all 512 blocks are co-resident regardless of dispatch order.
        k_mega<<<512, 256, 0, stream>>>(x, wxt, bias, whtf, xp, hbuf, out, bar);
    }
}